// Round 6
// baseline (427.582 us; speedup 1.0000x reference)
//
#include <hip/hip_runtime.h>

#define N_EDGES 1048576
#define N_GRAPH 512
#define MAXE    3072
#define HBLK    256          // hist/scatter blocks
#define CHUNK   4096         // edges per hist/scatter block

typedef __attribute__((ext_vector_type(4))) float floatx4;
typedef __attribute__((ext_vector_type(2))) float floatx2;

// ---------------- preprocessing: deterministic counting sort ----------------
// hist: per-block 512-graph histogram -> hp[block][512] (plain stores)
__global__ void hist_kernel(const int* __restrict__ dst, unsigned* __restrict__ hp) {
    __shared__ unsigned h[512];
    int t = threadIdx.x;
    h[t] = 0; h[t + 256] = 0;
    __syncthreads();
    int e0 = blockIdx.x * CHUNK;
    for (int i = t; i < CHUNK; i += 256)
        atomicAdd(&h[((unsigned)dst[e0 + i]) >> 7], 1u);
    __syncthreads();
    hp[blockIdx.x * 512 + t]       = h[t];
    hp[blockIdx.x * 512 + t + 256] = h[t + 256];
}

// scan: hp[b][g] -> global start offset for (block b, graph g); base[g] for mega
__global__ void scan_kernel(unsigned* __restrict__ hp, unsigned* __restrict__ base) {
    __shared__ unsigned s[512];
    int g = threadIdx.x;
    unsigned acc = 0;
#pragma unroll 8
    for (int b = 0; b < HBLK; ++b) {
        unsigned v = hp[b * 512 + g];
        hp[b * 512 + g] = acc;          // exclusive prefix within graph
        acc += v;
    }
    s[g] = acc;                          // total count for graph g
    __syncthreads();
    for (int d = 1; d < 512; d <<= 1) {
        unsigned v = (g >= d) ? s[g - d] : 0u;
        __syncthreads();
        s[g] += v;
        __syncthreads();
    }
    base[g + 1] = s[g];
    if (g == 0) base[0] = 0;
    unsigned bg = s[g] - acc;            // base[g]
#pragma unroll 8
    for (int b = 0; b < HBLK; ++b)
        hp[b * 512 + g] += bg;           // now absolute start for (b,g)
}

// scatter: LDS cursors seeded from hp -> no global atomics, ~8-edge runs per graph
__global__ void scatter_kernel(const int* __restrict__ src, const int* __restrict__ dst,
                               const unsigned* __restrict__ hp,
                               unsigned short* __restrict__ ebuf) {
    __shared__ unsigned cur[512];
    int t = threadIdx.x;
    cur[t]       = hp[blockIdx.x * 512 + t];
    cur[t + 256] = hp[blockIdx.x * 512 + t + 256];
    __syncthreads();
    int e0 = blockIdx.x * CHUNK;
    for (int i = t; i < CHUNK; i += 256) {
        int sv = src[e0 + i], dv = dst[e0 + i];
        unsigned pos = atomicAdd(&cur[((unsigned)dv) >> 7], 1u);
        ebuf[pos] = (unsigned short)((sv & 127) | ((dv & 127) << 8));
    }
}

// ---------------- fused per-graph GCN layer (register-tiled f32) ----------------
// 1024 thr = 32 node-groups (grp=tid>>5, 4 nodes each) x 32 channel-lanes (cg).
// TC = CTILE/32 channels/thread. X from LDS (or global for layer 1, XG=true),
// W from global (L1/L2-hot). H tile = 128 x CTILE. Aggregation reads H as
// float2 (TC=2) or float (TC=1), sym-normalized CSR + bias + tanh.
template<int CIN, int COUT, int CTILE, bool XG>
__device__ void gcn_layer(const float* __restrict__ Xin, float* __restrict__ Xout,
                          const float* __restrict__ W, const float* __restrict__ Bv,
                          float* __restrict__ H, const float* __restrict__ dinv,
                          const int* __restrict__ offs, const unsigned char* __restrict__ csr,
                          int tid)
{
    constexpr int TC = CTILE / 32;       // 2 or 1
    const int grp = tid >> 5, cg = tid & 31;

    for (int pass = 0; pass < COUT / CTILE; ++pass) {
        const int cbase = pass * CTILE;
        const int cme   = cbase + cg * TC;
        float acc[4][TC];
#pragma unroll
        for (int ni = 0; ni < 4; ++ni)
#pragma unroll
            for (int j = 0; j < TC; ++j) acc[ni][j] = 0.f;

#pragma unroll 2
        for (int k = 0; k < CIN; k += 4) {
            floatx4 xv[4];
#pragma unroll
            for (int ni = 0; ni < 4; ++ni)
                xv[ni] = *(const floatx4*)(Xin + (grp * 4 + ni) * CIN + k);
            float wv[4][TC];
#pragma unroll
            for (int i = 0; i < 4; ++i) {
                if constexpr (TC == 2) {
                    floatx2 w2 = *(const floatx2*)(W + (k + i) * COUT + cme);
                    wv[i][0] = w2[0]; wv[i][1] = w2[1];
                } else {
                    wv[i][0] = W[(k + i) * COUT + cme];
                }
            }
#pragma unroll
            for (int ni = 0; ni < 4; ++ni)
#pragma unroll
                for (int i = 0; i < 4; ++i)
#pragma unroll
                    for (int j = 0; j < TC; ++j)
                        acc[ni][j] += xv[ni][i] * wv[i][j];
        }
        __syncthreads();    // prev pass finished reading H
#pragma unroll
        for (int ni = 0; ni < 4; ++ni) {
            if constexpr (TC == 2) {
                floatx2 v; v[0] = acc[ni][0]; v[1] = acc[ni][1];
                *(floatx2*)(H + (grp * 4 + ni) * CTILE + cg * 2) = v;
            } else {
                H[(grp * 4 + ni) * CTILE + cg] = acc[ni][0];
            }
        }
        __syncthreads();

        float bias[TC];
#pragma unroll
        for (int j = 0; j < TC; ++j) bias[j] = Bv[cme + j];

        for (int ni = 0; ni < 4; ++ni) {
            int n = grp * 4 + ni;
            float dn = dinv[n];
            float a[TC];
#pragma unroll
            for (int j = 0; j < TC; ++j) a[j] = 0.f;
            int o0 = offs[n], o1 = offs[n + 1];
            for (int p = o0; p < o1; ++p) {
                int s = csr[p] & 127;
                float coef = dinv[s] * dn;
                if constexpr (TC == 2) {
                    floatx2 h2 = *(const floatx2*)(H + s * CTILE + cg * 2);
                    a[0] += h2[0] * coef; a[1] += h2[1] * coef;
                } else {
                    a[0] += H[s * CTILE + cg] * coef;
                }
            }
            float dnn = dn * dn;
#pragma unroll
            for (int j = 0; j < TC; ++j) {
                float v = a[j] + H[n * CTILE + cg * TC + j] * dnn + bias[j];
                v = tanhf(v);
                v = fminf(fmaxf(v, -1.0f), 1.0f);
                Xout[n * COUT + cme + j] = v;
            }
        }
    }
    __syncthreads();        // Xout complete before next layer / H reuse
}

// ---------------- fused per-graph kernel ----------------
__global__ __launch_bounds__(1024, 1) void mega_kernel(
    const float* __restrict__ x,
    const float* __restrict__ W1, const float* __restrict__ b1,
    const float* __restrict__ W2, const float* __restrict__ b2,
    const float* __restrict__ W3, const float* __restrict__ b3,
    const float* __restrict__ W4, const float* __restrict__ b4,
    const float* __restrict__ W5, const float* __restrict__ b5,
    const float* __restrict__ W6, const float* __restrict__ b6,
    const float* __restrict__ Wf1, const float* __restrict__ bf1,
    const float* __restrict__ Wf2, const float* __restrict__ bf2,
    const unsigned* __restrict__ base, const unsigned short* __restrict__ ebuf,
    float* __restrict__ out)
{
    __shared__ __align__(16) char pool[161792];
    int*   ldeg = (int*)(pool + 0);                      // int[128]
    int*   offs = (int*)(pool + 512);                    // int[129]
    float* dinv = (float*)(pool + 1040);                 // f32[128]
    float* key  = (float*)(pool + 1552);                 // f32[128]
    unsigned short* ord = (unsigned short*)(pool + 2064);// u16[64]
    unsigned char*  csr = (unsigned char*)(pool + 2192); // u8[3072]
    float* X1   = (float*)(pool + 6144);     // 128x128 (64 KB)
    float* X2   = (float*)(pool + 71680);    // 128x64  (32 KB)
    float* X3   = (float*)(pool + 104448);   // 128x32  (16 KB)
    float* X4   = (float*)(pool + 120832);   // 128x32  (16 KB)
    float* H12  = (float*)(pool + 104448);   // 128x64 tile (L1/L2) over X3+X4 slots
    float* H3   = (float*)(pool + 120832);   // 128x32 tile (L3) over X4 slot
    float* H4   = (float*)(pool + 137216);   // 128x32 tile (L4)
    float* W5s  = (float*)(pool + 137216);   // 16x256 (16 KB), after H4 dead
    float* SCR  = (float*)(pool + 153600);   // 8 KB phased tail scratch
    float* Zs   = SCR;                 // 16x64
    float* ZMP  = SCR + 1024;          // 16x32
    float* Z896 = SCR;                 // 896 (over dead Zs)
    float* PART = SCR + 1024;          // 8x128 (over dead ZMP)
    float* FC1  = SCR + 896;           // 128
    float* LG   = SCR;                 // 17 (over dead Z896 head)

    const int g   = blockIdx.x;
    const int tid = threadIdx.x;
    const unsigned base_g = base[g];
    int cnt = (int)(base[g + 1] - base_g);
    if (cnt < 0)    cnt = 0;
    if (cnt > MAXE) cnt = MAXE;

    // ---- build local CSR (by dst) ----
    if (tid < 128) ldeg[tid] = 0;
    __syncthreads();
    for (int e = tid; e < cnt; e += 1024) {
        unsigned v = ebuf[base_g + e];
        atomicAdd(&ldeg[(v >> 8) & 127], 1);
    }
    __syncthreads();
    if (tid < 128) offs[tid + 1] = ldeg[tid];
    if (tid == 0)  offs[0] = 0;
    __syncthreads();
    for (int d = 1; d < 128; d <<= 1) {
        int v = 0;
        if (tid < 128 && tid >= d) v = offs[tid + 1 - d];
        __syncthreads();
        if (tid < 128 && tid >= d) offs[tid + 1] += v;
        __syncthreads();
    }
    if (tid < 128) {
        dinv[tid] = 1.0f / sqrtf((float)(1 + ldeg[tid]));   // self-loop + in-degree
        ldeg[tid] = offs[tid];                               // repurpose as cursor
    }
    __syncthreads();
    for (int e = tid; e < cnt; e += 1024) {
        unsigned v = ebuf[base_g + e];
        int dn_ = (v >> 8) & 127, sn = v & 127;
        int p = atomicAdd(&ldeg[dn_], 1);
        csr[p] = (unsigned char)sn;
    }
    __syncthreads();

    // ---- 4 GCN layers (layer 1 reads x straight from global) ----
    const float* xg = x + (size_t)g * 128 * 128;
    gcn_layer<128, 128, 64, true >(xg, X1, W1, b1, H12, dinv, offs, csr, tid);
    gcn_layer<128,  64, 64, false>(X1, X2, W2, b2, H12, dinv, offs, csr, tid);
    gcn_layer< 64,  32, 32, false>(X2, X3, W3, b3, H3,  dinv, offs, csr, tid);
    gcn_layer< 32,  32, 32, false>(X3, X4, W4, b4, H4,  dinv, offs, csr, tid);

    // ---- sort key + stage W5 (over dead H4) ----
    if (tid < 128) key[tid] = X4[tid * 32 + 31];
    if (tid < 64)  ord[tid] = (unsigned short)tid;    // safety default
    for (int idx = tid; idx < 4096; idx += 1024) W5s[idx] = W5[idx];
    __syncthreads();
    // stable descending rank (= jnp.argsort(-key) first 64)
    if (tid < 128) {
        float myk = key[tid];
        int r = 0;
        for (int j = 0; j < 128; ++j) {
            float kj = key[j];
            r += (kj > myk) || (kj == myk && j < tid);
        }
        if (r < 64) ord[r] = (unsigned short)tid;
    }
    __syncthreads();

    // ---- z = relu(Conv1d(1,16,256,256)) on pooled rows ----
    {
        int q = tid >> 6, t = tid & 63;          // q: channel, t: pooled node slot
        int node = ord[t] & 127;
        float z0 = b5[q];
        const float* w5a = W5s + q * 256;
        for (int jj = 0; jj < 128; ++jj) {       // lane-rotated: spread banks
            int j = (jj + t) & 127;
            z0 += X1[node * 128 + j] * w5a[j];
        }
        for (int jj = 0; jj < 64; ++jj) {
            int j = (jj + t) & 63;
            z0 += X2[node * 64 + j] * w5a[128 + j];
        }
        for (int jj = 0; jj < 32; ++jj) {
            int j = (jj + t) & 31;
            z0 += X3[node * 32 + j] * w5a[192 + j];
        }
        for (int jj = 0; jj < 32; ++jj) {
            int j = (jj + t) & 31;
            z0 += X4[node * 32 + j] * w5a[224 + j];
        }
        Zs[q * 64 + t] = fmaxf(z0, 0.f);
    }
    __syncthreads();
    // ---- maxpool(2,2) ----
    if (tid < 512) {
        int c = tid >> 5, p = tid & 31;
        ZMP[c * 32 + p] = fmaxf(Zs[c * 64 + 2 * p], Zs[c * 64 + 2 * p + 1]);
    }
    __syncthreads();
    // ---- stage W6 (over dead W5s) ----
    for (int idx = tid; idx < 2560; idx += 1024) W5s[idx] = W6[idx];
    __syncthreads();
    // ---- conv1d(16,32,5) VALID + relu ----
    if (tid < 896) {
        int oc = tid / 28, p = tid % 28;
        float s = b6[oc];
#pragma unroll
        for (int i = 0; i < 16; ++i) {
            const float* wrow = W5s + (oc * 16 + i) * 5;
#pragma unroll
            for (int k = 0; k < 5; ++k)
                s += ZMP[i * 32 + p + k] * wrow[k];
        }
        Z896[tid] = fmaxf(s, 0.f);               // over dead Zs
    }
    __syncthreads();
    // ---- fc1 (896->128), split-K x8 ----
    {
        int f = tid & 127, q = tid >> 7;
        float s = 0.f;
        for (int i = q * 112; i < (q + 1) * 112; ++i)
            s += Z896[i] * Wf1[i * 128 + f];
        PART[q * 128 + f] = s;                   // over dead ZMP
    }
    __syncthreads();
    if (tid < 128) {
        float s = bf1[tid];
#pragma unroll
        for (int q = 0; q < 8; ++q) s += PART[q * 128 + tid];
        FC1[tid] = fmaxf(s, 0.f);
    }
    __syncthreads();
    // ---- fc2 (128->10) + log_softmax ----
    if (tid < 10) {
        float s = bf2[tid];
        for (int i = 0; i < 128; ++i) s += FC1[i] * Wf2[i * 10 + tid];
        LG[tid] = s;
    }
    __syncthreads();
    if (tid == 0) {
        float mx = LG[0];
        for (int i = 1; i < 10; ++i) mx = fmaxf(mx, LG[i]);
        float se = 0.f;
        for (int i = 0; i < 10; ++i) se += expf(LG[i] - mx);
        LG[16] = mx + logf(se);
    }
    __syncthreads();
    if (tid < 10)
        out[g * 10 + tid] = LG[tid] - LG[16];
}

extern "C" void kernel_launch(void* const* d_in, const int* in_sizes, int n_in,
                              void* d_out, int out_size, void* d_ws, size_t ws_size,
                              hipStream_t stream) {
    (void)in_sizes; (void)n_in; (void)out_size; (void)ws_size;
    const float* x   = (const float*)d_in[0];
    const float* W1  = (const float*)d_in[1];
    const float* b1  = (const float*)d_in[2];
    const float* W2  = (const float*)d_in[3];
    const float* b2  = (const float*)d_in[4];
    const float* W3  = (const float*)d_in[5];
    const float* b3  = (const float*)d_in[6];
    const float* W4  = (const float*)d_in[7];
    const float* b4  = (const float*)d_in[8];
    const float* W5  = (const float*)d_in[9];
    const float* b5  = (const float*)d_in[10];
    const float* W6  = (const float*)d_in[11];
    const float* b6  = (const float*)d_in[12];
    const float* Wf1 = (const float*)d_in[13];
    const float* bf1 = (const float*)d_in[14];
    const float* Wf2 = (const float*)d_in[15];
    const float* bf2 = (const float*)d_in[16];
    const int* ei  = (const int*)d_in[17];
    const int* src = ei;
    const int* dst = ei + N_EDGES;

    char* ws = (char*)d_ws;
    unsigned* hp          = (unsigned*)(ws);                  // 256*512 u32 = 512 KB
    unsigned* base        = (unsigned*)(ws + 524288);         // u32[513]
    unsigned short* ebuf  = (unsigned short*)(ws + 527360);   // u16[E] = 2 MB

    hist_kernel<<<HBLK, 256, 0, stream>>>(dst, hp);
    scan_kernel<<<1, 512, 0, stream>>>(hp, base);
    scatter_kernel<<<HBLK, 256, 0, stream>>>(src, dst, hp, ebuf);
    mega_kernel<<<N_GRAPH, 1024, 0, stream>>>(x, W1, b1, W2, b2, W3, b3, W4, b4,
                                              W5, b5, W6, b6, Wf1, bf1, Wf2, bf2,
                                              base, ebuf, (float*)d_out);
}

// Round 7
// 343.202 us; speedup vs baseline: 1.2459x; 1.2459x over previous
//
#include <hip/hip_runtime.h>

#define N_EDGES 1048576
#define N_GRAPH 512
#define MAXE    3072
#define HBLK    256          // hist/scatter blocks
#define CHUNK   4096         // edges per hist/scatter block

typedef __attribute__((ext_vector_type(4))) float floatx4;
typedef __attribute__((ext_vector_type(2))) float floatx2;
typedef __attribute__((ext_vector_type(4))) int intx4;

// ---------------- preprocessing: deterministic counting sort ----------------
__global__ void hist_kernel(const int* __restrict__ dst, unsigned* __restrict__ hp) {
    __shared__ unsigned h[512];
    int t = threadIdx.x;
    h[t] = 0; h[t + 256] = 0;
    __syncthreads();
    const intx4* d4 = (const intx4*)(dst + blockIdx.x * CHUNK);
    for (int i = t; i < CHUNK / 4; i += 256) {
        intx4 d = d4[i];
        atomicAdd(&h[((unsigned)d.x) >> 7], 1u);
        atomicAdd(&h[((unsigned)d.y) >> 7], 1u);
        atomicAdd(&h[((unsigned)d.z) >> 7], 1u);
        atomicAdd(&h[((unsigned)d.w) >> 7], 1u);
    }
    __syncthreads();
    hp[blockIdx.x * 512 + t]       = h[t];
    hp[blockIdx.x * 512 + t + 256] = h[t + 256];
}

__global__ void scan_kernel(unsigned* __restrict__ hp, unsigned* __restrict__ base) {
    __shared__ unsigned s[512];
    int g = threadIdx.x;
    unsigned acc = 0;
#pragma unroll 8
    for (int b = 0; b < HBLK; ++b) {
        unsigned v = hp[b * 512 + g];
        hp[b * 512 + g] = acc;
        acc += v;
    }
    s[g] = acc;
    __syncthreads();
    for (int d = 1; d < 512; d <<= 1) {
        unsigned v = (g >= d) ? s[g - d] : 0u;
        __syncthreads();
        s[g] += v;
        __syncthreads();
    }
    base[g + 1] = s[g];
    if (g == 0) base[0] = 0;
    unsigned bg = s[g] - acc;
#pragma unroll 8
    for (int b = 0; b < HBLK; ++b)
        hp[b * 512 + g] += bg;
}

__global__ void scatter_kernel(const int* __restrict__ src, const int* __restrict__ dst,
                               const unsigned* __restrict__ hp,
                               unsigned short* __restrict__ ebuf) {
    __shared__ unsigned cur[512];
    int t = threadIdx.x;
    cur[t]       = hp[blockIdx.x * 512 + t];
    cur[t + 256] = hp[blockIdx.x * 512 + t + 256];
    __syncthreads();
    const intx4* s4 = (const intx4*)(src + blockIdx.x * CHUNK);
    const intx4* d4 = (const intx4*)(dst + blockIdx.x * CHUNK);
    for (int i = t; i < CHUNK / 4; i += 256) {
        intx4 sv = s4[i], dv = d4[i];
        int ss[4] = {sv.x, sv.y, sv.z, sv.w};
        int dd[4] = {dv.x, dv.y, dv.z, dv.w};
#pragma unroll
        for (int j = 0; j < 4; ++j) {
            unsigned pos = atomicAdd(&cur[((unsigned)dd[j]) >> 7], 1u);
            ebuf[pos] = (unsigned short)((ss[j] & 127) | ((dd[j] & 127) << 8));
        }
    }
}

// ---------------- generic GCN layer (L2-L4): Xin in LDS ----------------
// 32 node-groups x 32 ch-lanes; lane cg holds channels cg*TPL..+TPL-1.
// H stored as TPL planes of 128x32 (conflict-free b32 aggregation reads).
template<int CIN, int COUT>
__device__ void gcn_layer(const float* __restrict__ Xin, float* __restrict__ Xout,
                          const float* __restrict__ W, const float* __restrict__ Bv,
                          float* __restrict__ H, const float* __restrict__ dinv,
                          const int* __restrict__ offs, const unsigned char* __restrict__ csr,
                          int tid)
{
    constexpr int TPL = COUT / 32;     // 2 or 1
    const int grp = tid >> 5, cg = tid & 31;
    float acc[4][TPL];
#pragma unroll
    for (int ni = 0; ni < 4; ++ni)
#pragma unroll
        for (int j = 0; j < TPL; ++j) acc[ni][j] = 0.f;

    for (int k = 0; k < CIN; k += 4) {
        floatx4 xv[4];
#pragma unroll
        for (int ni = 0; ni < 4; ++ni)
            xv[ni] = *(const floatx4*)(Xin + (grp * 4 + ni) * CIN + k);
#pragma unroll
        for (int i = 0; i < 4; ++i) {
            float wv[TPL];
            if constexpr (TPL == 2) {
                floatx2 w2 = *(const floatx2*)(W + (k + i) * COUT + cg * 2);
                wv[0] = w2[0]; wv[1] = w2[1];
            } else {
                wv[0] = W[(k + i) * COUT + cg];
            }
#pragma unroll
            for (int ni = 0; ni < 4; ++ni)
#pragma unroll
                for (int j = 0; j < TPL; ++j)
                    acc[ni][j] += xv[ni][i] * wv[j];
        }
    }
    __syncthreads();                   // H region free (prev layer done with it)
#pragma unroll
    for (int ni = 0; ni < 4; ++ni)
#pragma unroll
        for (int j = 0; j < TPL; ++j)
            H[j * 4096 + (grp * 4 + ni) * 32 + cg] = acc[ni][j];
    __syncthreads();

    float bias[TPL];
#pragma unroll
    for (int j = 0; j < TPL; ++j) bias[j] = Bv[cg * TPL + j];

    for (int ni = 0; ni < 4; ++ni) {
        int n = grp * 4 + ni;
        float dn = dinv[n];
        float a[TPL];
#pragma unroll
        for (int j = 0; j < TPL; ++j) a[j] = 0.f;
        int o0 = offs[n], o1 = offs[n + 1];
        for (int p = o0; p < o1; ++p) {
            int s = csr[p] & 127;
            float coef = dinv[s] * dn;
#pragma unroll
            for (int j = 0; j < TPL; ++j)
                a[j] += H[j * 4096 + s * 32 + cg] * coef;
        }
        float dnn = dn * dn;
        float v[TPL];
#pragma unroll
        for (int j = 0; j < TPL; ++j) {
            float t2 = a[j] + acc[ni][j] * dnn + bias[j];
            t2 = tanhf(t2);
            v[j] = fminf(fmaxf(t2, -1.0f), 1.0f);
        }
        if constexpr (TPL == 2) {
            floatx2 o; o[0] = v[0]; o[1] = v[1];
            *(floatx2*)(Xout + n * COUT + cg * 2) = o;
        } else {
            Xout[n * COUT + cg] = v[0];
        }
    }
    __syncthreads();                   // Xout complete for next consumer
}

// ---------------- fused per-graph kernel ----------------
__global__ __launch_bounds__(1024, 1) void mega_kernel(
    const float* __restrict__ x,
    const float* __restrict__ W1, const float* __restrict__ b1,
    const float* __restrict__ W2, const float* __restrict__ b2,
    const float* __restrict__ W3, const float* __restrict__ b3,
    const float* __restrict__ W4, const float* __restrict__ b4,
    const float* __restrict__ W5, const float* __restrict__ b5,
    const float* __restrict__ W6, const float* __restrict__ b6,
    const float* __restrict__ Wf1, const float* __restrict__ bf1,
    const float* __restrict__ Wf2, const float* __restrict__ bf2,
    const unsigned* __restrict__ base, const unsigned short* __restrict__ ebuf,
    float* __restrict__ out)
{
    __shared__ __align__(16) char pool[161792];
    int*   ldeg = (int*)(pool + 0);                      // int[128]
    int*   offs = (int*)(pool + 512);                    // int[129]
    float* dinv = (float*)(pool + 1040);                 // f32[128]
    float* key  = (float*)(pool + 1552);                 // f32[128]
    unsigned short* ord = (unsigned short*)(pool + 2064);// u16[64]
    unsigned char*  csr = (unsigned char*)(pool + 2192); // u8[3072]
    float* X1   = (float*)(pool + 6144);     // 128x128 (64 KB)
    float* B0   = (float*)(pool + 71680);    // L1 stage buf 0 (16 KB)
    float* B1   = (float*)(pool + 88064);    // L1 stage buf 1 (16 KB)
    float* X2   = (float*)(pool + 71680);    // 128x64 (32 KB) after L1
    float* H    = (float*)(pool + 104448);   // 2 planes x 128x32 (32 KB): L1/L2
    float* X3   = (float*)(pool + 120832);   // 128x32 (16 KB) — L3 out (H then 16 KB)
    float* X4   = (float*)(pool + 137216);   // 128x32 (16 KB) — L4 out
    float* W5s  = (float*)(pool + 104448);   // 16x256 (16 KB) over dead H (tail)
    float* SCR  = (float*)(pool + 153600);   // 8 KB phased tail scratch
    float* Zs   = SCR;                 // 16x64
    float* ZMP  = SCR + 1024;          // 16x32
    float* Z896 = SCR;                 // 896 (over dead Zs)
    float* PART = SCR + 1024;          // 8x128 (over dead ZMP)
    float* FC1  = SCR + 896;           // 128
    float* LG   = SCR;                 // 17 (over dead Z896 head)

    const int g   = blockIdx.x;
    const int tid = threadIdx.x;
    const unsigned base_g = base[g];
    int cnt = (int)(base[g + 1] - base_g);
    if (cnt < 0)    cnt = 0;
    if (cnt > MAXE) cnt = MAXE;

    // ---- build local CSR (by dst) ----
    if (tid < 128) ldeg[tid] = 0;
    __syncthreads();
    for (int e = tid; e < cnt; e += 1024) {
        unsigned v = ebuf[base_g + e];
        atomicAdd(&ldeg[(v >> 8) & 127], 1);
    }
    __syncthreads();
    if (tid < 128) offs[tid + 1] = ldeg[tid];
    if (tid == 0)  offs[0] = 0;
    __syncthreads();
    for (int d = 1; d < 128; d <<= 1) {
        int v = 0;
        if (tid < 128 && tid >= d) v = offs[tid + 1 - d];
        __syncthreads();
        if (tid < 128 && tid >= d) offs[tid + 1] += v;
        __syncthreads();
    }
    if (tid < 128) {
        dinv[tid] = 1.0f / sqrtf((float)(1 + ldeg[tid]));
        ldeg[tid] = offs[tid];
    }
    __syncthreads();
    for (int e = tid; e < cnt; e += 1024) {
        unsigned v = ebuf[base_g + e];
        int dn_ = (v >> 8) & 127, sn = v & 127;
        int p = atomicAdd(&ldeg[dn_], 1);
        csr[p] = (unsigned char)sn;
    }
    __syncthreads();

    // ---- Layer 1: staged double-buffered x, full 128-ch register sweep ----
    {
        const float* xg = x + (size_t)g * 16384;
        const int grp = tid >> 5, cg = tid & 31;
        const int srow = tid >> 3, skq = tid & 7;     // staging map: 1 float4/thread
        float acc[4][4];
#pragma unroll
        for (int ni = 0; ni < 4; ++ni)
#pragma unroll
            for (int j = 0; j < 4; ++j) acc[ni][j] = 0.f;

        floatx4 r = *(const floatx4*)(xg + srow * 128 + skq * 4);   // chunk 0
        *(floatx4*)(B0 + srow * 32 + skq * 4) = r;
        for (int c = 0; c < 4; ++c) {
            __syncthreads();          // chunk c staged & visible; prev readers done
            if (c < 3)
                r = *(const floatx4*)(xg + srow * 128 + (c + 1) * 32 + skq * 4);
            const float* Xc = (c & 1) ? B1 : B0;
#pragma unroll 2
            for (int kk = 0; kk < 32; kk += 4) {
                floatx4 xv[4];
#pragma unroll
                for (int ni = 0; ni < 4; ++ni)
                    xv[ni] = *(const floatx4*)(Xc + (grp * 4 + ni) * 32 + kk);
#pragma unroll
                for (int i = 0; i < 4; ++i) {
                    floatx4 wv = *(const floatx4*)(W1 + (c * 32 + kk + i) * 128 + cg * 4);
#pragma unroll
                    for (int ni = 0; ni < 4; ++ni)
#pragma unroll
                        for (int j = 0; j < 4; ++j)
                            acc[ni][j] += xv[ni][i] * wv[j];
                }
            }
            if (c < 3)
                *(floatx4*)(((c & 1) ? B0 : B1) + srow * 32 + skq * 4) = r;
        }
        // two aggregation passes (H = 2 planes of 128x32)
#pragma unroll
        for (int P = 0; P < 2; ++P) {
            __syncthreads();
#pragma unroll
            for (int ni = 0; ni < 4; ++ni) {
                H[(grp * 4 + ni) * 32 + cg]        = acc[ni][P * 2];
                H[4096 + (grp * 4 + ni) * 32 + cg] = acc[ni][P * 2 + 1];
            }
            __syncthreads();
            float bias0 = b1[cg * 4 + P * 2], bias1 = b1[cg * 4 + P * 2 + 1];
            for (int ni = 0; ni < 4; ++ni) {
                int n = grp * 4 + ni;
                float dn = dinv[n];
                float a0 = 0.f, a1 = 0.f;
                int o0 = offs[n], o1 = offs[n + 1];
                for (int p = o0; p < o1; ++p) {
                    int s = csr[p] & 127;
                    float coef = dinv[s] * dn;
                    a0 += H[s * 32 + cg] * coef;
                    a1 += H[4096 + s * 32 + cg] * coef;
                }
                float dnn = dn * dn;
                float v0 = tanhf(a0 + acc[ni][P * 2]     * dnn + bias0);
                float v1 = tanhf(a1 + acc[ni][P * 2 + 1] * dnn + bias1);
                v0 = fminf(fmaxf(v0, -1.0f), 1.0f);
                v1 = fminf(fmaxf(v1, -1.0f), 1.0f);
                floatx2 o; o[0] = v0; o[1] = v1;
                *(floatx2*)(X1 + n * 128 + cg * 4 + P * 2) = o;
            }
        }
        __syncthreads();
    }

    // ---- Layers 2-4 ----
    gcn_layer<128, 64>(X1, X2, W2, b2, H, dinv, offs, csr, tid);
    gcn_layer< 64, 32>(X2, X3, W3, b3, H, dinv, offs, csr, tid);
    gcn_layer< 32, 32>(X3, X4, W4, b4, H, dinv, offs, csr, tid);

    // ---- sort key + stage W5 (over dead H) ----
    if (tid < 128) key[tid] = X4[tid * 32 + 31];
    if (tid < 64)  ord[tid] = (unsigned short)tid;
    for (int idx = tid; idx < 4096; idx += 1024) W5s[idx] = W5[idx];
    __syncthreads();
    if (tid < 128) {
        float myk = key[tid];
        int r = 0;
        for (int j = 0; j < 128; ++j) {
            float kj = key[j];
            r += (kj > myk) || (kj == myk && j < tid);
        }
        if (r < 64) ord[r] = (unsigned short)tid;
    }
    __syncthreads();

    // ---- z = relu(Conv1d(1,16,256,256)) on pooled rows ----
    {
        int q = tid >> 6, t = tid & 63;
        int node = ord[t] & 127;
        float z0 = b5[q];
        const float* w5a = W5s + q * 256;
        for (int jj = 0; jj < 128; ++jj) {
            int j = (jj + t) & 127;
            z0 += X1[node * 128 + j] * w5a[j];
        }
        for (int jj = 0; jj < 64; ++jj) {
            int j = (jj + t) & 63;
            z0 += X2[node * 64 + j] * w5a[128 + j];
        }
        for (int jj = 0; jj < 32; ++jj) {
            int j = (jj + t) & 31;
            z0 += X3[node * 32 + j] * w5a[192 + j];
        }
        for (int jj = 0; jj < 32; ++jj) {
            int j = (jj + t) & 31;
            z0 += X4[node * 32 + j] * w5a[224 + j];
        }
        Zs[q * 64 + t] = fmaxf(z0, 0.f);
    }
    __syncthreads();
    // ---- maxpool(2,2) ----
    if (tid < 512) {
        int c = tid >> 5, p = tid & 31;
        ZMP[c * 32 + p] = fmaxf(Zs[c * 64 + 2 * p], Zs[c * 64 + 2 * p + 1]);
    }
    __syncthreads();
    // ---- stage W6 (over dead W5s) ----
    for (int idx = tid; idx < 2560; idx += 1024) W5s[idx] = W6[idx];
    __syncthreads();
    // ---- conv1d(16,32,5) VALID + relu ----
    if (tid < 896) {
        int oc = tid / 28, p = tid % 28;
        float s = b6[oc];
#pragma unroll
        for (int i = 0; i < 16; ++i) {
            const float* wrow = W5s + (oc * 16 + i) * 5;
#pragma unroll
            for (int k = 0; k < 5; ++k)
                s += ZMP[i * 32 + p + k] * wrow[k];
        }
        Z896[tid] = fmaxf(s, 0.f);
    }
    __syncthreads();
    // ---- fc1 (896->128), split-K x8 ----
    {
        int f = tid & 127, q = tid >> 7;
        float s = 0.f;
        for (int i = q * 112; i < (q + 1) * 112; ++i)
            s += Z896[i] * Wf1[i * 128 + f];
        PART[q * 128 + f] = s;
    }
    __syncthreads();
    if (tid < 128) {
        float s = bf1[tid];
#pragma unroll
        for (int q = 0; q < 8; ++q) s += PART[q * 128 + tid];
        FC1[tid] = fmaxf(s, 0.f);
    }
    __syncthreads();
    // ---- fc2 (128->10) + log_softmax ----
    if (tid < 10) {
        float s = bf2[tid];
        for (int i = 0; i < 128; ++i) s += FC1[i] * Wf2[i * 10 + tid];
        LG[tid] = s;
    }
    __syncthreads();
    if (tid == 0) {
        float mx = LG[0];
        for (int i = 1; i < 10; ++i) mx = fmaxf(mx, LG[i]);
        float se = 0.f;
        for (int i = 0; i < 10; ++i) se += expf(LG[i] - mx);
        LG[16] = mx + logf(se);
    }
    __syncthreads();
    if (tid < 10)
        out[g * 10 + tid] = LG[tid] - LG[16];
}

extern "C" void kernel_launch(void* const* d_in, const int* in_sizes, int n_in,
                              void* d_out, int out_size, void* d_ws, size_t ws_size,
                              hipStream_t stream) {
    (void)in_sizes; (void)n_in; (void)out_size; (void)ws_size;
    const float* x   = (const float*)d_in[0];
    const float* W1  = (const float*)d_in[1];
    const float* b1  = (const float*)d_in[2];
    const float* W2  = (const float*)d_in[3];
    const float* b2  = (const float*)d_in[4];
    const float* W3  = (const float*)d_in[5];
    const float* b3  = (const float*)d_in[6];
    const float* W4  = (const float*)d_in[7];
    const float* b4  = (const float*)d_in[8];
    const float* W5  = (const float*)d_in[9];
    const float* b5  = (const float*)d_in[10];
    const float* W6  = (const float*)d_in[11];
    const float* b6  = (const float*)d_in[12];
    const float* Wf1 = (const float*)d_in[13];
    const float* bf1 = (const float*)d_in[14];
    const float* Wf2 = (const float*)d_in[15];
    const float* bf2 = (const float*)d_in[16];
    const int* ei  = (const int*)d_in[17];
    const int* src = ei;
    const int* dst = ei + N_EDGES;

    char* ws = (char*)d_ws;
    unsigned* hp          = (unsigned*)(ws);                  // 256*512 u32 = 512 KB
    unsigned* base        = (unsigned*)(ws + 524288);         // u32[513]
    unsigned short* ebuf  = (unsigned short*)(ws + 527360);   // u16[E] = 2 MB

    hist_kernel<<<HBLK, 256, 0, stream>>>(dst, hp);
    scan_kernel<<<1, 512, 0, stream>>>(hp, base);
    scatter_kernel<<<HBLK, 256, 0, stream>>>(src, dst, hp, ebuf);
    mega_kernel<<<N_GRAPH, 1024, 0, stream>>>(x, W1, b1, W2, b2, W3, b3, W4, b4,
                                              W5, b5, W6, b6, Wf1, bf1, Wf2, bf2,
                                              base, ebuf, (float*)d_out);
}

// Round 8
// 285.263 us; speedup vs baseline: 1.4989x; 1.2031x over previous
//
#include <hip/hip_runtime.h>

#define N_EDGES 1048576
#define N_GRAPH 512
#define REG     2560         // per-graph ebuf capacity (mean 2048, +11 sigma)
#define MAXE    2560
#define PAD     64           // cursor padding (u32) = 256 B
#define CHUNK   4096         // edges per scatter block

typedef __attribute__((ext_vector_type(4))) float floatx4;
typedef __attribute__((ext_vector_type(4))) int intx4;

// ---------------- preprocessing ----------------
__global__ void zero_kernel(unsigned* __restrict__ p, int n) {
    int i = blockIdx.x * blockDim.x + threadIdx.x;
    if (i < n) p[i] = 0u;
}

// one-pass scatter: LDS hist -> one global atomic per (block,graph) run -> write
__global__ void scatter1p_kernel(const int* __restrict__ src, const int* __restrict__ dst,
                                 unsigned* __restrict__ cnt, unsigned short* __restrict__ ebuf) {
    __shared__ unsigned lhist[512];
    __shared__ unsigned lbase[512];
    int t = threadIdx.x;
    lhist[t] = 0; lhist[t + 256] = 0;
    __syncthreads();
    const intx4* s4 = (const intx4*)(src + blockIdx.x * CHUNK);
    const intx4* d4 = (const intx4*)(dst + blockIdx.x * CHUNK);
    unsigned gg[16]; unsigned short pk[16]; unsigned rr[16];
    int m = 0;
    for (int i = t; i < CHUNK / 4; i += 256) {
        intx4 sv = s4[i], dv = d4[i];
        int ss[4] = {sv.x, sv.y, sv.z, sv.w};
        int dd[4] = {dv.x, dv.y, dv.z, dv.w};
#pragma unroll
        for (int j = 0; j < 4; ++j) {
            unsigned g = ((unsigned)dd[j]) >> 7;
            gg[m] = g;
            pk[m] = (unsigned short)((ss[j] & 127) | ((dd[j] & 127) << 8));
            rr[m] = atomicAdd(&lhist[g], 1u);
            ++m;
        }
    }
    __syncthreads();
    lbase[t]       = lhist[t]       ? atomicAdd(&cnt[(size_t)t * PAD],         lhist[t])       : 0u;
    lbase[t + 256] = lhist[t + 256] ? atomicAdd(&cnt[(size_t)(t + 256) * PAD], lhist[t + 256]) : 0u;
    __syncthreads();
#pragma unroll
    for (int j = 0; j < 16; ++j) {
        unsigned pos = lbase[gg[j]] + rr[j];
        if (pos < REG) ebuf[(size_t)gg[j] * REG + pos] = pk[j];
    }
}

// ---------------- GCN layer: in-place H, float4 channels ----------------
// threads 1024 = NG groups x CL channel-lanes; CL=COUT/4, NPT=CL/8 nodes/thread.
// matmul acc in regs -> barrier -> write H into Xio -> barrier -> aggregate
// (1 coef + 1 csr broadcast + 1 b128 per edge) into regs -> barrier ->
// tanh output overwrites Xio.
template<int CIN, int COUT>
__device__ void gcn_layer(const float* Xin, float* Xio,
                          const float* __restrict__ W, const float* __restrict__ Bv,
                          const float* __restrict__ dinv, const int* __restrict__ offs,
                          const unsigned char* __restrict__ csr,
                          const float* __restrict__ ecoef, int tid)
{
    constexpr int CL  = COUT / 4;
    constexpr int NPT = CL / 8;
    const int grp = tid / CL, cl = tid % CL;

    float acc[NPT][4];
#pragma unroll
    for (int ni = 0; ni < NPT; ++ni)
#pragma unroll
        for (int j = 0; j < 4; ++j) acc[ni][j] = 0.f;

    for (int k = 0; k < CIN; k += 4) {
        floatx4 xv[NPT];
#pragma unroll
        for (int ni = 0; ni < NPT; ++ni)
            xv[ni] = *(const floatx4*)(Xin + (grp * NPT + ni) * CIN + k);
#pragma unroll
        for (int i = 0; i < 4; ++i) {
            floatx4 wv = *(const floatx4*)(W + (k + i) * COUT + cl * 4);
#pragma unroll
            for (int ni = 0; ni < NPT; ++ni)
#pragma unroll
                for (int j = 0; j < 4; ++j)
                    acc[ni][j] += xv[ni][i] * wv[j];
        }
    }
    __syncthreads();                 // everyone done reading Xin (may alias Xio)
#pragma unroll
    for (int ni = 0; ni < NPT; ++ni) {
        floatx4 v; v[0] = acc[ni][0]; v[1] = acc[ni][1]; v[2] = acc[ni][2]; v[3] = acc[ni][3];
        *(floatx4*)(Xio + (grp * NPT + ni) * COUT + cl * 4) = v;
    }
    __syncthreads();

    floatx4 bv = *(const floatx4*)(Bv + cl * 4);
    float vout[NPT][4];
#pragma unroll
    for (int ni = 0; ni < NPT; ++ni) {
        int n = grp * NPT + ni;
        float dn = dinv[n];
        float a[4] = {0.f, 0.f, 0.f, 0.f};
        int o0 = offs[n], o1 = offs[n + 1];
        for (int p = o0; p < o1; ++p) {
            int s = csr[p] & 127;
            float cf = ecoef[p];
            floatx4 h = *(const floatx4*)(Xio + s * COUT + cl * 4);
#pragma unroll
            for (int j = 0; j < 4; ++j) a[j] += h[j] * cf;
        }
        float dnn = dn * dn;
#pragma unroll
        for (int j = 0; j < 4; ++j) {
            float t2 = a[j] + acc[ni][j] * dnn + bv[j];
            t2 = tanhf(t2);
            vout[ni][j] = fminf(fmaxf(t2, -1.0f), 1.0f);
        }
    }
    __syncthreads();                 // all aggregation reads done
#pragma unroll
    for (int ni = 0; ni < NPT; ++ni) {
        floatx4 v; v[0] = vout[ni][0]; v[1] = vout[ni][1]; v[2] = vout[ni][2]; v[3] = vout[ni][3];
        *(floatx4*)(Xio + (grp * NPT + ni) * COUT + cl * 4) = v;
    }
    __syncthreads();
}

// ---------------- fused per-graph kernel ----------------
__global__ __launch_bounds__(1024, 1) void mega_kernel(
    const float* __restrict__ x,
    const float* __restrict__ W1, const float* __restrict__ b1,
    const float* __restrict__ W2, const float* __restrict__ b2,
    const float* __restrict__ W3, const float* __restrict__ b3,
    const float* __restrict__ W4, const float* __restrict__ b4,
    const float* __restrict__ W5, const float* __restrict__ b5,
    const float* __restrict__ W6, const float* __restrict__ b6,
    const float* __restrict__ Wf1, const float* __restrict__ bf1,
    const float* __restrict__ Wf2, const float* __restrict__ bf2,
    const unsigned* __restrict__ cnt, const unsigned short* __restrict__ ebuf,
    float* __restrict__ out)
{
    __shared__ __align__(16) char pool[157952];
    int*   ldeg = (int*)(pool + 0);                       // int[128]
    int*   offs = (int*)(pool + 512);                     // int[129]
    float* dinv = (float*)(pool + 1040);                  // f32[128]
    float* key  = (float*)(pool + 1552);                  // f32[128]
    unsigned short* ord = (unsigned short*)(pool + 2064); // u16[64]
    unsigned char*  csr = (unsigned char*)(pool + 2304);  // u8[2560] (in R region)
    float* ecoef = (float*)(pool + 2304 + 2560 + 16);     // f32[2560] (align16)
    float* W5s   = (float*)(pool + 2304);                 // 16x256 f32 (16 KB) over R region (tail)
    float* X1   = (float*)(pool + 18688);    // 128x128 (64 KB)
    float* X2   = (float*)(pool + 84224);    // 128x64  (32 KB)
    float* X3   = (float*)(pool + 116992);   // 128x32  (16 KB)
    float* X4   = (float*)(pool + 133376);   // 128x32  (16 KB)
    float* SCR  = (float*)(pool + 149760);   // 8 KB phased tail scratch
    float* Zs   = SCR;                 // 16x64
    float* ZMP  = SCR + 1024;          // 16x32
    float* Z896 = SCR;                 // 896 (over dead Zs)
    float* PART = SCR + 1024;          // 8x128 (over dead ZMP)
    float* FC1  = SCR + 896;           // 128
    float* LG   = SCR;                 // 17 (over dead Z896 head)

    const int g   = blockIdx.x;
    const int tid = threadIdx.x;
    int cnt_g = (int)cnt[(size_t)g * PAD];
    if (cnt_g > MAXE) cnt_g = MAXE;
    const unsigned short* eg = ebuf + (size_t)g * REG;

    // ---- load this thread's edges (<=3) into regs ----
    unsigned short ev[3]; int ne = 0;
    for (int e = tid; e < cnt_g; e += 1024) ev[ne++] = eg[e];

    // ---- degree histogram ----
    if (tid < 128) ldeg[tid] = 0;
    __syncthreads();
    for (int i = 0; i < ne; ++i) atomicAdd(&ldeg[(ev[i] >> 8) & 127], 1);
    __syncthreads();
    if (tid < 128) offs[tid + 1] = ldeg[tid];
    if (tid == 0)  offs[0] = 0;
    __syncthreads();
    for (int d = 1; d < 128; d <<= 1) {
        int v = 0;
        if (tid < 128 && tid >= d) v = offs[tid + 1 - d];
        __syncthreads();
        if (tid < 128 && tid >= d) offs[tid + 1] += v;
        __syncthreads();
    }
    if (tid < 128) {
        dinv[tid] = 1.0f / sqrtf((float)(1 + ldeg[tid]));  // self-loop + in-degree
        ldeg[tid] = offs[tid];                              // repurpose as cursor
    }
    __syncthreads();
    // ---- scatter into CSR + per-edge coef ----
    for (int i = 0; i < ne; ++i) {
        int dn_ = (ev[i] >> 8) & 127, sn = ev[i] & 127;
        int p = atomicAdd(&ldeg[dn_], 1);
        csr[p]   = (unsigned char)sn;
        ecoef[p] = dinv[sn] * dinv[dn_];
    }
    // ---- stage x into X1 (layer-1 runs in-place there) ----
    const float* xg = x + (size_t)g * 16384;
    for (int idx = tid; idx < 4096; idx += 1024)
        *(floatx4*)(X1 + idx * 4) = *(const floatx4*)(xg + idx * 4);
    __syncthreads();

    // ---- 4 GCN layers (in-place H) ----
    gcn_layer<128, 128>(X1, X1, W1, b1, dinv, offs, csr, ecoef, tid);
    gcn_layer<128,  64>(X1, X2, W2, b2, dinv, offs, csr, ecoef, tid);
    gcn_layer< 64,  32>(X2, X3, W3, b3, dinv, offs, csr, ecoef, tid);
    gcn_layer< 32,  32>(X3, X4, W4, b4, dinv, offs, csr, ecoef, tid);

    // ---- sort key + stage W5 (over dead csr/ecoef region) ----
    if (tid < 128) key[tid] = X4[tid * 32 + 31];
    if (tid < 64)  ord[tid] = (unsigned short)tid;
    __syncthreads();                   // csr/ecoef fully dead before overwrite
    for (int idx = tid; idx < 4096; idx += 1024) W5s[idx] = W5[idx];
    __syncthreads();
    if (tid < 128) {
        float myk = key[tid];
        int r = 0;
        for (int j = 0; j < 128; ++j) {
            float kj = key[j];
            r += (kj > myk) || (kj == myk && j < tid);
        }
        if (r < 64) ord[r] = (unsigned short)tid;
    }
    __syncthreads();

    // ---- z = relu(Conv1d(1,16,256,256)), float4 ----
    {
        int q = tid >> 6, t = tid & 63;
        int node = ord[t] & 127;
        float z0 = b5[q];
        const float* w5a = W5s + q * 256;
        floatx4 zv = {0.f, 0.f, 0.f, 0.f};
        for (int jj = 0; jj < 32; ++jj) {
            int j = (jj + t) & 31;
            floatx4 pv = *(const floatx4*)(X1 + node * 128 + j * 4);
            floatx4 wv = *(const floatx4*)(w5a + j * 4);
#pragma unroll
            for (int u = 0; u < 4; ++u) zv[u] += pv[u] * wv[u];
        }
        for (int jj = 0; jj < 16; ++jj) {
            int j = (jj + t) & 15;
            floatx4 pv = *(const floatx4*)(X2 + node * 64 + j * 4);
            floatx4 wv = *(const floatx4*)(w5a + 128 + j * 4);
#pragma unroll
            for (int u = 0; u < 4; ++u) zv[u] += pv[u] * wv[u];
        }
        for (int jj = 0; jj < 8; ++jj) {
            int j = (jj + t) & 7;
            floatx4 pv = *(const floatx4*)(X3 + node * 32 + j * 4);
            floatx4 wv = *(const floatx4*)(w5a + 192 + j * 4);
#pragma unroll
            for (int u = 0; u < 4; ++u) zv[u] += pv[u] * wv[u];
        }
        for (int jj = 0; jj < 8; ++jj) {
            int j = (jj + t) & 7;
            floatx4 pv = *(const floatx4*)(X4 + node * 32 + j * 4);
            floatx4 wv = *(const floatx4*)(w5a + 224 + j * 4);
#pragma unroll
            for (int u = 0; u < 4; ++u) zv[u] += pv[u] * wv[u];
        }
        z0 += zv[0] + zv[1] + zv[2] + zv[3];
        Zs[q * 64 + t] = fmaxf(z0, 0.f);
    }
    __syncthreads();
    // ---- maxpool(2,2) ----
    if (tid < 512) {
        int c = tid >> 5, p = tid & 31;
        ZMP[c * 32 + p] = fmaxf(Zs[c * 64 + 2 * p], Zs[c * 64 + 2 * p + 1]);
    }
    __syncthreads();
    // ---- stage W6 (over dead W5s) ----
    for (int idx = tid; idx < 2560; idx += 1024) W5s[idx] = W6[idx];
    __syncthreads();
    // ---- conv1d(16,32,5) VALID + relu ----
    if (tid < 896) {
        int oc = tid / 28, p = tid % 28;
        float s = b6[oc];
#pragma unroll
        for (int i = 0; i < 16; ++i) {
            const float* wrow = W5s + (oc * 16 + i) * 5;
#pragma unroll
            for (int k = 0; k < 5; ++k)
                s += ZMP[i * 32 + p + k] * wrow[k];
        }
        Z896[tid] = fmaxf(s, 0.f);
    }
    __syncthreads();
    // ---- fc1 (896->128), split-K x8 ----
    {
        int f = tid & 127, q = tid >> 7;
        float s = 0.f;
        for (int i = q * 112; i < (q + 1) * 112; ++i)
            s += Z896[i] * Wf1[i * 128 + f];
        PART[q * 128 + f] = s;
    }
    __syncthreads();
    if (tid < 128) {
        float s = bf1[tid];
#pragma unroll
        for (int q = 0; q < 8; ++q) s += PART[q * 128 + tid];
        FC1[tid] = fmaxf(s, 0.f);
    }
    __syncthreads();
    // ---- fc2 (128->10) + log_softmax ----
    if (tid < 10) {
        float s = bf2[tid];
        for (int i = 0; i < 128; ++i) s += FC1[i] * Wf2[i * 10 + tid];
        LG[tid] = s;
    }
    __syncthreads();
    if (tid == 0) {
        float mx = LG[0];
        for (int i = 1; i < 10; ++i) mx = fmaxf(mx, LG[i]);
        float se = 0.f;
        for (int i = 0; i < 10; ++i) se += expf(LG[i] - mx);
        LG[16] = mx + logf(se);
    }
    __syncthreads();
    if (tid < 10)
        out[g * 10 + tid] = LG[tid] - LG[16];
}

extern "C" void kernel_launch(void* const* d_in, const int* in_sizes, int n_in,
                              void* d_out, int out_size, void* d_ws, size_t ws_size,
                              hipStream_t stream) {
    (void)in_sizes; (void)n_in; (void)out_size; (void)ws_size;
    const float* x   = (const float*)d_in[0];
    const float* W1  = (const float*)d_in[1];
    const float* b1  = (const float*)d_in[2];
    const float* W2  = (const float*)d_in[3];
    const float* b2  = (const float*)d_in[4];
    const float* W3  = (const float*)d_in[5];
    const float* b3  = (const float*)d_in[6];
    const float* W4  = (const float*)d_in[7];
    const float* b4  = (const float*)d_in[8];
    const float* W5  = (const float*)d_in[9];
    const float* b5  = (const float*)d_in[10];
    const float* W6  = (const float*)d_in[11];
    const float* b6  = (const float*)d_in[12];
    const float* Wf1 = (const float*)d_in[13];
    const float* bf1 = (const float*)d_in[14];
    const float* Wf2 = (const float*)d_in[15];
    const float* bf2 = (const float*)d_in[16];
    const int* ei  = (const int*)d_in[17];
    const int* src = ei;
    const int* dst = ei + N_EDGES;

    char* ws = (char*)d_ws;
    unsigned* cnt         = (unsigned*)(ws);                  // 512*PAD u32 = 128 KB
    unsigned short* ebuf  = (unsigned short*)(ws + 131072);   // u16[512*REG] = 2.5 MB

    zero_kernel<<<32, 1024, 0, stream>>>(cnt, 512 * PAD);
    scatter1p_kernel<<<N_EDGES / CHUNK, 256, 0, stream>>>(src, dst, cnt, ebuf);
    mega_kernel<<<N_GRAPH, 1024, 0, stream>>>(x, W1, b1, W2, b2, W3, b3, W4, b4,
                                              W5, b5, W6, b6, Wf1, bf1, Wf2, bf2,
                                              cnt, ebuf, (float*)d_out);
}